// Round 2
// baseline (1584.045 us; speedup 1.0000x reference)
//
#include <hip/hip_runtime.h>
#include <hip/hip_bf16.h>

#define AST_DIM 256
#define NR_AST 500000
#define NR_CFG 100000
#define NR_MAP 400000
#define BM 64
#define NT_TILES (NR_MAP / BM)   // 6250
#define NBLK 512                 // 2 blocks/CU exactly

typedef short short8 __attribute__((ext_vector_type(8)));
typedef float f32x4 __attribute__((ext_vector_type(4)));
typedef unsigned long long u64;

__device__ __forceinline__ unsigned short f2bf(float f) {
    unsigned int u = __float_as_uint(f);
    u += 0x7FFFu + ((u >> 16) & 1u);   // RNE
    return (unsigned short)(u >> 16);
}
__device__ __forceinline__ float bf2f(unsigned short s) {
    return __uint_as_float(((unsigned int)s) << 16);
}
__device__ __forceinline__ u64 pack4(float4 v) {
    __hip_bfloat162 lo = __float22bfloat162_rn(float2{v.x, v.y});  // v_cvt_pk_bf16_f32
    __hip_bfloat162 hi = __float22bfloat162_rn(float2{v.z, v.w});
    unsigned int lu = *(unsigned int*)&lo;
    unsigned int hu = *(unsigned int*)&hi;
    return (u64)lu | ((u64)hu << 32);
}
__device__ __forceinline__ float fast_tanh(float x) {
    return 1.f - 2.f * __builtin_amdgcn_rcpf(__expf(2.f * x) + 1.f);
}
__device__ __forceinline__ float fast_sigmoid(float x) {
    return __builtin_amdgcn_rcpf(1.f + __expf(-x));
}
__device__ __forceinline__ void wait_lds_barrier() {
    asm volatile("s_waitcnt lgkmcnt(0)" ::: "memory");
    __builtin_amdgcn_s_barrier();
}

// W_update / W_gate (f32, [K][N]) -> bf16 transposed [N][K].
// ws layout: [0]=Wt_update, [1]=Wt_gate_top (k<256), [2]=Wt_gate_bot.
__global__ void convert_w(const float* __restrict__ Wu, const float* __restrict__ Wg,
                          unsigned short* __restrict__ wt) {
    int idx = blockIdx.x * 256 + threadIdx.x;
    if (idx >= 3 * 65536) return;
    int m = idx >> 16;
    int r = idx & 65535;
    int n = r >> 8;
    int k = r & 255;
    float v;
    if (m == 0)      v = Wu[k * 256 + n];
    else if (m == 1) v = Wg[k * 256 + n];
    else             v = Wg[(k + 256) * 256 + n];
    wt[idx] = f2bf(v);
}

__global__ void set_mask(const int* __restrict__ keys, unsigned char* __restrict__ mask) {
    int i = blockIdx.x * 256 + threadIdx.x;
    if (i < NR_MAP) mask[keys[i]] = 1;
}

__global__ void copy_unmapped(const float* __restrict__ prev,
                              const unsigned char* __restrict__ mask,
                              float* __restrict__ out) {
    const long long total = (long long)NR_AST * 64;  // float4 units
    for (long long i = (long long)blockIdx.x * blockDim.x + threadIdx.x; i < total;
         i += (long long)gridDim.x * blockDim.x) {
        int row = (int)(i >> 6);
        if (!mask[row])
            ((float4*)out)[i] = ((const float4*)prev)[i];
    }
}

// Persistent pipelined mixer: 512 blocks x 512 threads (8 waves), 64 rows/tile,
// ~12 tiles per block. Gathers for tile t+1 are in flight during compute of
// tile t (reg-staged, bf16-converted at natural vmcnt wait points). Raw
// s_barrier (no vmcnt drain) keeps the prefetch alive across barriers.
__global__ __launch_bounds__(512, 4) void mixer_main(
    const float* __restrict__ prev, const float* __restrict__ cfg,
    const int* __restrict__ keys, const int* __restrict__ vals,
    const unsigned short* __restrict__ Wtu, const unsigned short* __restrict__ Wtgt,
    const unsigned short* __restrict__ Wtgb, const float* __restrict__ bu,
    const float* __restrict__ bg, float* __restrict__ out) {
    __shared__ __align__(16) unsigned char ctx_lds[64 * 512];  // ctx, then u (aliased)
    __shared__ __align__(16) unsigned char prv_lds[64 * 512];

    const int tid = threadIdx.x;
    const int lane = tid & 63;
    const int wave = tid >> 6;
    const int ln15 = lane & 15;
    const int khi = lane >> 4;
    const int cb = wave * 32;

    // hoisted biases (tile-invariant)
    const float bu_r0 = bu[cb + ln15], bu_r1 = bu[cb + 16 + ln15];
    const float bg_r0 = bg[cb + ln15], bg_r1 = bg[cb + 16 + ln15];

    int t = blockIdx.x;
    // ---- prologue: indices + gather for tile t; indices for t+NBLK ----
    int kA = keys[t * BM + lane];           // keys of tile t (epilogue scatter)
    int vA = vals[t * BM + lane];
    float4 pc[8], pp[8];
#pragma unroll
    for (int i = 0; i < 8; ++i) {
        int r = i * 8 + wave;
        pc[i] = *((const float4*)(cfg + (size_t)__shfl(vA, r) * AST_DIM) + lane);
        pp[i] = *((const float4*)(prev + (size_t)__shfl(kA, r) * AST_DIM) + lane);
    }
    int tn = t + NBLK;
    int tc = tn < NT_TILES ? tn : NT_TILES - 1;
    int kB = keys[tc * BM + lane];          // keys/vals of tile t+NBLK
    int vB = vals[tc * BM + lane];
    u64 pcb[8], ppb[8];
#pragma unroll
    for (int i = 0; i < 8; ++i) pcb[i] = pack4(pc[i]);
#pragma unroll
    for (int i = 0; i < 8; ++i) ppb[i] = pack4(pp[i]);

#pragma unroll 1
    for (; t < NT_TILES; t += NBLK) {
        tn = t + NBLK;
        const bool more = (tn < NT_TILES);

        // ---- 1. pack tile t (already bf16 in regs) -> LDS ----
#pragma unroll
        for (int i = 0; i < 8; ++i) {
            int r = i * 8 + wave;
            int addr = (r << 9) + (lane << 3);
            addr ^= (r & 7) << 4;  // XOR swizzle (16B granularity)
            *(u64*)(ctx_lds + addr) = pcb[i];
            *(u64*)(prv_lds + addr) = ppb[i];
        }
        // ---- 2. issue ctx gather for tile tn; prefetch indices for tn+NBLK ----
        if (more) {
#pragma unroll
            for (int i = 0; i < 8; ++i) {
                int r = i * 8 + wave;
                pc[i] = *((const float4*)(cfg + (size_t)__shfl(vB, r) * AST_DIM) + lane);
            }
        }
        int tnn = tn + NBLK;
        tnn = tnn < NT_TILES ? tnn : NT_TILES - 1;
        int kC = keys[tnn * BM + lane];
        int vC = vals[tnn * BM + lane];

        wait_lds_barrier();  // pack visible to all waves (no vmcnt drain!)

        // ---- 4. GEMM1: u_pre = ctx @ Wu + bu ----
        f32x4 acc[4][2];
#pragma unroll
        for (int mt = 0; mt < 4; ++mt) {
            acc[mt][0] = f32x4{bu_r0, bu_r0, bu_r0, bu_r0};
            acc[mt][1] = f32x4{bu_r1, bu_r1, bu_r1, bu_r1};
        }
#pragma unroll
        for (int ks = 0; ks < 8; ++ks) {
            short8 a[4], b[2];
            for (int mt = 0; mt < 4; ++mt) {
                int row = mt * 16 + ln15;
                int addr = (row << 9) + (ks << 6) + (khi << 4);
                addr ^= (row & 7) << 4;
                a[mt] = *(const short8*)(ctx_lds + addr);
            }
            for (int nt = 0; nt < 2; ++nt)
                b[nt] = *(const short8*)(Wtu + (cb + nt * 16 + ln15) * 256 + ks * 32 + khi * 8);
            for (int mt = 0; mt < 4; ++mt)
                for (int nt = 0; nt < 2; ++nt)
                    acc[mt][nt] = __builtin_amdgcn_mfma_f32_16x16x32_bf16(a[mt], b[nt], acc[mt][nt], 0, 0, 0);
        }
        // ---- 5. ctx(tn) has arrived under GEMM1: convert to bf16, free f32 regs ----
        if (more) {
#pragma unroll
            for (int i = 0; i < 8; ++i) pcb[i] = pack4(pc[i]);
        }
        wait_lds_barrier();  // all waves done reading ctx tile

        // ---- 6. tanh; write u (bf16) into ctx_lds region ----
#pragma unroll
        for (int mt = 0; mt < 4; ++mt)
            for (int rr = 0; rr < 4; ++rr) {
                int row = mt * 16 + khi * 4 + rr;
                for (int nt = 0; nt < 2; ++nt) {
                    int col = cb + nt * 16 + ln15;
                    int addr = (row << 9) + (col << 1);
                    addr ^= (row & 7) << 4;
                    *(unsigned short*)(ctx_lds + addr) = f2bf(fast_tanh(acc[mt][nt][rr]));
                }
            }
        wait_lds_barrier();  // u visible

        // ---- 7. issue prev gather for tile tn (covered by GEMM2) ----
        if (more) {
#pragma unroll
            for (int i = 0; i < 8; ++i) {
                int r = i * 8 + wave;
                pp[i] = *((const float4*)(prev + (size_t)__shfl(kB, r) * AST_DIM) + lane);
            }
        }
        // ---- 8. GEMM2: z_pre = prev @ Wg_top + u @ Wg_bot + bg ----
#pragma unroll
        for (int mt = 0; mt < 4; ++mt) {
            acc[mt][0] = f32x4{bg_r0, bg_r0, bg_r0, bg_r0};
            acc[mt][1] = f32x4{bg_r1, bg_r1, bg_r1, bg_r1};
        }
#pragma unroll
        for (int ks = 0; ks < 8; ++ks) {
            short8 a[4], b[2];
            for (int mt = 0; mt < 4; ++mt) {
                int row = mt * 16 + ln15;
                int addr = (row << 9) + (ks << 6) + (khi << 4);
                addr ^= (row & 7) << 4;
                a[mt] = *(const short8*)(prv_lds + addr);
            }
            for (int nt = 0; nt < 2; ++nt)
                b[nt] = *(const short8*)(Wtgt + (cb + nt * 16 + ln15) * 256 + ks * 32 + khi * 8);
            for (int mt = 0; mt < 4; ++mt)
                for (int nt = 0; nt < 2; ++nt)
                    acc[mt][nt] = __builtin_amdgcn_mfma_f32_16x16x32_bf16(a[mt], b[nt], acc[mt][nt], 0, 0, 0);
        }
#pragma unroll
        for (int ks = 0; ks < 8; ++ks) {
            short8 a[4], b[2];
            for (int mt = 0; mt < 4; ++mt) {
                int row = mt * 16 + ln15;
                int addr = (row << 9) + (ks << 6) + (khi << 4);
                addr ^= (row & 7) << 4;
                a[mt] = *(const short8*)(ctx_lds + addr);  // u
            }
            for (int nt = 0; nt < 2; ++nt)
                b[nt] = *(const short8*)(Wtgb + (cb + nt * 16 + ln15) * 256 + ks * 32 + khi * 8);
            for (int mt = 0; mt < 4; ++mt)
                for (int nt = 0; nt < 2; ++nt)
                    acc[mt][nt] = __builtin_amdgcn_mfma_f32_16x16x32_bf16(a[mt], b[nt], acc[mt][nt], 0, 0, 0);
        }
        // ---- 9. epilogue: sigmoid, blend, scatter store (keys via shfl) ----
#pragma unroll
        for (int mt = 0; mt < 4; ++mt)
            for (int rr = 0; rr < 4; ++rr) {
                int row = mt * 16 + khi * 4 + rr;
                int key = __shfl(kA, row);
                float* orow = out + (size_t)key * AST_DIM;
                for (int nt = 0; nt < 2; ++nt) {
                    int col = cb + nt * 16 + ln15;
                    int ad = (row << 9) + (col << 1);
                    ad ^= (row & 7) << 4;
                    float z = fast_sigmoid(acc[mt][nt][rr]);
                    float pf = bf2f(*(const unsigned short*)(prv_lds + ad));
                    float uv = bf2f(*(const unsigned short*)(ctx_lds + ad));
                    orow[col] = fmaf(z, pf - uv, uv);  // z*prev + (1-z)*u
                }
            }
        // ---- 10. prev(tn) arrived under GEMM2: convert ----
        if (more) {
#pragma unroll
            for (int i = 0; i < 8; ++i) ppb[i] = pack4(pp[i]);
        }
        wait_lds_barrier();  // protect LDS tiles until all waves done reading

        // rotate index registers
        kA = kB; kB = kC; vB = vC;
    }
}

extern "C" void kernel_launch(void* const* d_in, const int* in_sizes, int n_in,
                              void* d_out, int out_size, void* d_ws, size_t ws_size,
                              hipStream_t stream) {
    const float* prev = (const float*)d_in[0];
    const float* cfg = (const float*)d_in[1];
    const int* keys = (const int*)d_in[2];
    const int* vals = (const int*)d_in[3];
    const float* Wu = (const float*)d_in[4];
    const float* bu = (const float*)d_in[5];
    const float* Wg = (const float*)d_in[6];
    const float* bg = (const float*)d_in[7];
    float* out = (float*)d_out;

    unsigned short* wt = (unsigned short*)d_ws;                    // 3*65536 bf16
    unsigned char* mask = (unsigned char*)d_ws + 3 * 65536 * 2;    // NR_AST bytes

    hipMemsetAsync(mask, 0, NR_AST, stream);
    convert_w<<<768, 256, 0, stream>>>(Wu, Wg, wt);
    set_mask<<<(NR_MAP + 255) / 256, 256, 0, stream>>>(keys, mask);
    copy_unmapped<<<2048, 256, 0, stream>>>(prev, mask, out);
    mixer_main<<<NBLK, 512, 0, stream>>>(prev, cfg, keys, vals, wt, wt + 65536,
                                         wt + 2 * 65536, bu, bg, out);
}

// Round 4
// 1086.299 us; speedup vs baseline: 1.4582x; 1.4582x over previous
//
#include <hip/hip_runtime.h>
#include <hip/hip_bf16.h>

#define AST_DIM 256
#define NR_AST 500000
#define NR_CFG 100000
#define NR_MAP 400000
#define BM 64
#define NT_TILES (NR_MAP / BM)   // 6250
#define NBLK 512

typedef short short8 __attribute__((ext_vector_type(8)));
typedef float f32x4 __attribute__((ext_vector_type(4)));
typedef unsigned long long u64;

__device__ __forceinline__ unsigned short f2bf(float f) {
    unsigned int u = __float_as_uint(f);
    u += 0x7FFFu + ((u >> 16) & 1u);   // RNE
    return (unsigned short)(u >> 16);
}
__device__ __forceinline__ float bf2f(unsigned short s) {
    return __uint_as_float(((unsigned int)s) << 16);
}
__device__ __forceinline__ u64 pack4(f32x4 v) {
    __hip_bfloat162 lo = __float22bfloat162_rn(float2{v.x, v.y});  // v_cvt_pk_bf16_f32
    __hip_bfloat162 hi = __float22bfloat162_rn(float2{v.z, v.w});
    unsigned int lu = *(unsigned int*)&lo;
    unsigned int hu = *(unsigned int*)&hi;
    return (u64)lu | ((u64)hu << 32);
}
__device__ __forceinline__ float fast_tanh(float x) {
    return 1.f - 2.f * __builtin_amdgcn_rcpf(__expf(2.f * x) + 1.f);
}
__device__ __forceinline__ float fast_sigmoid(float x) {
    return __builtin_amdgcn_rcpf(1.f + __expf(-x));
}
__device__ __forceinline__ void wait_lds_barrier() {
    asm volatile("s_waitcnt lgkmcnt(0)" ::: "memory");
    __builtin_amdgcn_s_barrier();
}

// W_update / W_gate (f32, [K][N]) -> bf16 transposed [N][K].
// ws layout: [0]=Wt_update, [1]=Wt_gate_top (k<256), [2]=Wt_gate_bot.
__global__ void convert_w(const float* __restrict__ Wu, const float* __restrict__ Wg,
                          unsigned short* __restrict__ wt) {
    int idx = blockIdx.x * 256 + threadIdx.x;
    if (idx >= 3 * 65536) return;
    int m = idx >> 16;
    int r = idx & 65535;
    int n = r >> 8;
    int k = r & 255;
    float v;
    if (m == 0)      v = Wu[k * 256 + n];
    else if (m == 1) v = Wg[k * 256 + n];
    else             v = Wg[(k + 256) * 256 + n];
    wt[idx] = f2bf(v);
}

__global__ void set_mask(const int* __restrict__ keys, unsigned char* __restrict__ mask) {
    int i = blockIdx.x * 256 + threadIdx.x;
    if (i < NR_MAP) mask[keys[i]] = 1;
}

__global__ void copy_unmapped(const float* __restrict__ prev,
                              const unsigned char* __restrict__ mask,
                              float* __restrict__ out) {
    const long long total = (long long)NR_AST * 64;  // f32x4 units
    for (long long i = (long long)blockIdx.x * blockDim.x + threadIdx.x; i < total;
         i += (long long)gridDim.x * blockDim.x) {
        int row = (int)(i >> 6);
        if (!mask[row]) {
            f32x4 v = __builtin_nontemporal_load((const f32x4*)prev + i);
            __builtin_nontemporal_store(v, (f32x4*)out + i);
        }
    }
}

// Persistent pipelined mixer: 512 blocks x 512 threads (8 waves), 64 rows/tile.
// Gathers for tile t+1 fly during compute of tile t (reg-staged, converted to
// bf16 at points covered by the GEMMs). Raw s_barrier (lgkmcnt only, NO vmcnt
// drain) keeps prefetch loads alive across barriers.
// __launch_bounds__(512,3): VGPR cap ~170 — fits the ~150 live regs WITHOUT
// spilling (round 2's 128-cap spilled ~96 regs/thread -> +3 GB scratch traffic).
__global__ __launch_bounds__(512, 3) void mixer_main(
    const float* __restrict__ prev, const float* __restrict__ cfg,
    const int* __restrict__ keys, const int* __restrict__ vals,
    const unsigned short* __restrict__ Wtu, const unsigned short* __restrict__ Wtgt,
    const unsigned short* __restrict__ Wtgb, const float* __restrict__ bu,
    const float* __restrict__ bg, float* __restrict__ out) {
    __shared__ __align__(16) unsigned char ctx_lds[64 * 512];  // ctx, then u (aliased)
    __shared__ __align__(16) unsigned char prv_lds[64 * 512];

    const int tid = threadIdx.x;
    const int lane = tid & 63;
    const int wave = tid >> 6;
    const int ln15 = lane & 15;
    const int khi = lane >> 4;
    const int cb = wave * 32;

    const float bu_r0 = bu[cb + ln15], bu_r1 = bu[cb + 16 + ln15];
    const float bg_r0 = bg[cb + ln15], bg_r1 = bg[cb + 16 + ln15];

    int t = blockIdx.x;
    // ---- prologue: indices + gather for tile t; indices for t+NBLK ----
    int kA = keys[t * BM + lane];
    int vA = vals[t * BM + lane];
    f32x4 pc[8], pp[8];
#pragma unroll
    for (int i = 0; i < 8; ++i) {
        int r = i * 8 + wave;
        pc[i] = *((const f32x4*)(cfg + (size_t)__shfl(vA, r) * AST_DIM) + lane);
        pp[i] = __builtin_nontemporal_load((const f32x4*)(prev + (size_t)__shfl(kA, r) * AST_DIM) + lane);
    }
    int tn = t + NBLK;
    int tc = tn < NT_TILES ? tn : NT_TILES - 1;
    int kB = keys[tc * BM + lane];
    int vB = vals[tc * BM + lane];
    u64 pcb[8], ppb[8];
#pragma unroll
    for (int i = 0; i < 8; ++i) pcb[i] = pack4(pc[i]);
#pragma unroll
    for (int i = 0; i < 8; ++i) ppb[i] = pack4(pp[i]);

#pragma unroll 1
    for (; t < NT_TILES; t += NBLK) {
        tn = t + NBLK;
        const bool more = (tn < NT_TILES);

        // ---- 1. pack tile t (bf16 in regs) -> LDS ----
#pragma unroll
        for (int i = 0; i < 8; ++i) {
            int r = i * 8 + wave;
            int addr = (r << 9) + (lane << 3);
            addr ^= (r & 7) << 4;  // XOR swizzle (16B granularity)
            *(u64*)(ctx_lds + addr) = pcb[i];
            *(u64*)(prv_lds + addr) = ppb[i];
        }
        // ---- 2. issue ctx gather for tile tn; prefetch indices for tn+NBLK ----
        if (more) {
#pragma unroll
            for (int i = 0; i < 8; ++i) {
                int r = i * 8 + wave;
                pc[i] = *((const f32x4*)(cfg + (size_t)__shfl(vB, r) * AST_DIM) + lane);
            }
        }
        int tnn = tn + NBLK;
        tnn = tnn < NT_TILES ? tnn : NT_TILES - 1;
        int kC = keys[tnn * BM + lane];
        int vC = vals[tnn * BM + lane];

        wait_lds_barrier();  // pack visible (no vmcnt drain)

        // ---- 4. GEMM1: u_pre = ctx @ Wu + bu ----
        f32x4 acc[4][2];
#pragma unroll
        for (int mt = 0; mt < 4; ++mt) {
            acc[mt][0] = f32x4{bu_r0, bu_r0, bu_r0, bu_r0};
            acc[mt][1] = f32x4{bu_r1, bu_r1, bu_r1, bu_r1};
        }
#pragma unroll
        for (int ks = 0; ks < 8; ++ks) {
            short8 a[4], b[2];
            for (int mt = 0; mt < 4; ++mt) {
                int row = mt * 16 + ln15;
                int addr = (row << 9) + (ks << 6) + (khi << 4);
                addr ^= (row & 7) << 4;
                a[mt] = *(const short8*)(ctx_lds + addr);
            }
            for (int nt = 0; nt < 2; ++nt)
                b[nt] = *(const short8*)(Wtu + (cb + nt * 16 + ln15) * 256 + ks * 32 + khi * 8);
            for (int mt = 0; mt < 4; ++mt)
                for (int nt = 0; nt < 2; ++nt)
                    acc[mt][nt] = __builtin_amdgcn_mfma_f32_16x16x32_bf16(a[mt], b[nt], acc[mt][nt], 0, 0, 0);
        }
        // ---- 5. ctx(tn) arrived under GEMM1: convert, free f32 regs ----
        if (more) {
#pragma unroll
            for (int i = 0; i < 8; ++i) pcb[i] = pack4(pc[i]);
        }
        wait_lds_barrier();  // all waves done reading ctx tile

        // ---- 6. tanh; write u (bf16) into ctx_lds region ----
#pragma unroll
        for (int mt = 0; mt < 4; ++mt)
            for (int rr = 0; rr < 4; ++rr) {
                int row = mt * 16 + khi * 4 + rr;
                for (int nt = 0; nt < 2; ++nt) {
                    int col = cb + nt * 16 + ln15;
                    int addr = (row << 9) + (col << 1);
                    addr ^= (row & 7) << 4;
                    *(unsigned short*)(ctx_lds + addr) = f2bf(fast_tanh(acc[mt][nt][rr]));
                }
            }
        wait_lds_barrier();  // u visible

        // ---- 7. issue prev gather for tile tn (covered by GEMM2) ----
        if (more) {
#pragma unroll
            for (int i = 0; i < 8; ++i) {
                int r = i * 8 + wave;
                pp[i] = __builtin_nontemporal_load(
                    (const f32x4*)(prev + (size_t)__shfl(kB, r) * AST_DIM) + lane);
            }
        }
        // ---- 8. GEMM2: z_pre = prev @ Wg_top + u @ Wg_bot + bg ----
#pragma unroll
        for (int mt = 0; mt < 4; ++mt) {
            acc[mt][0] = f32x4{bg_r0, bg_r0, bg_r0, bg_r0};
            acc[mt][1] = f32x4{bg_r1, bg_r1, bg_r1, bg_r1};
        }
#pragma unroll
        for (int ks = 0; ks < 8; ++ks) {
            short8 a[4], b[2];
            for (int mt = 0; mt < 4; ++mt) {
                int row = mt * 16 + ln15;
                int addr = (row << 9) + (ks << 6) + (khi << 4);
                addr ^= (row & 7) << 4;
                a[mt] = *(const short8*)(prv_lds + addr);
            }
            for (int nt = 0; nt < 2; ++nt)
                b[nt] = *(const short8*)(Wtgt + (cb + nt * 16 + ln15) * 256 + ks * 32 + khi * 8);
            for (int mt = 0; mt < 4; ++mt)
                for (int nt = 0; nt < 2; ++nt)
                    acc[mt][nt] = __builtin_amdgcn_mfma_f32_16x16x32_bf16(a[mt], b[nt], acc[mt][nt], 0, 0, 0);
        }
#pragma unroll
        for (int ks = 0; ks < 8; ++ks) {
            short8 a[4], b[2];
            for (int mt = 0; mt < 4; ++mt) {
                int row = mt * 16 + ln15;
                int addr = (row << 9) + (ks << 6) + (khi << 4);
                addr ^= (row & 7) << 4;
                a[mt] = *(const short8*)(ctx_lds + addr);  // u
            }
            for (int nt = 0; nt < 2; ++nt)
                b[nt] = *(const short8*)(Wtgb + (cb + nt * 16 + ln15) * 256 + ks * 32 + khi * 8);
            for (int mt = 0; mt < 4; ++mt)
                for (int nt = 0; nt < 2; ++nt)
                    acc[mt][nt] = __builtin_amdgcn_mfma_f32_16x16x32_bf16(a[mt], b[nt], acc[mt][nt], 0, 0, 0);
        }
        // ---- 9. epilogue: sigmoid, blend, scatter store ----
#pragma unroll
        for (int mt = 0; mt < 4; ++mt)
            for (int rr = 0; rr < 4; ++rr) {
                int row = mt * 16 + khi * 4 + rr;
                int key = __shfl(kA, row);
                float* orow = out + (size_t)key * AST_DIM;
                for (int nt = 0; nt < 2; ++nt) {
                    int col = cb + nt * 16 + ln15;
                    int ad = (row << 9) + (col << 1);
                    ad ^= (row & 7) << 4;
                    float z = fast_sigmoid(acc[mt][nt][rr]);
                    float pf = bf2f(*(const unsigned short*)(prv_lds + ad));
                    float uv = bf2f(*(const unsigned short*)(ctx_lds + ad));
                    __builtin_nontemporal_store(fmaf(z, pf - uv, uv), orow + col);
                }
            }
        // ---- 10. prev(tn) arrived under GEMM2: convert ----
        if (more) {
#pragma unroll
            for (int i = 0; i < 8; ++i) ppb[i] = pack4(pp[i]);
        }
        wait_lds_barrier();  // protect LDS tiles until all waves done reading

        kA = kB; kB = kC; vB = vC;
    }
}

extern "C" void kernel_launch(void* const* d_in, const int* in_sizes, int n_in,
                              void* d_out, int out_size, void* d_ws, size_t ws_size,
                              hipStream_t stream) {
    const float* prev = (const float*)d_in[0];
    const float* cfg = (const float*)d_in[1];
    const int* keys = (const int*)d_in[2];
    const int* vals = (const int*)d_in[3];
    const float* Wu = (const float*)d_in[4];
    const float* bu = (const float*)d_in[5];
    const float* Wg = (const float*)d_in[6];
    const float* bg = (const float*)d_in[7];
    float* out = (float*)d_out;

    unsigned short* wt = (unsigned short*)d_ws;                    // 3*65536 bf16
    unsigned char* mask = (unsigned char*)d_ws + 3 * 65536 * 2;    // NR_AST bytes

    (void)hipMemsetAsync(mask, 0, NR_AST, stream);
    convert_w<<<768, 256, 0, stream>>>(Wu, Wg, wt);
    set_mask<<<(NR_MAP + 255) / 256, 256, 0, stream>>>(keys, mask);
    copy_unmapped<<<2048, 256, 0, stream>>>(prev, mask, out);
    mixer_main<<<NBLK, 512, 0, stream>>>(prev, cfg, keys, vals, wt, wt + 65536,
                                         wt + 2 * 65536, bu, bg, out);
}

// Round 5
// 792.131 us; speedup vs baseline: 1.9997x; 1.3714x over previous
//
#include <hip/hip_runtime.h>
#include <hip/hip_bf16.h>

#define AST_DIM 256
#define NR_AST 500000
#define NR_CFG 100000
#define NR_MAP 400000
#define BM 32
#define NT_TILES (NR_MAP / BM)   // 12500
#define NBLK 256                 // persistent: 1 block/CU

typedef short short8 __attribute__((ext_vector_type(8)));
typedef float f32x4 __attribute__((ext_vector_type(4)));
typedef unsigned int u32x4 __attribute__((ext_vector_type(4)));
typedef unsigned long long u64;
typedef unsigned int u32;

__device__ __forceinline__ unsigned short f2bf(float f) {
    u32 u = __float_as_uint(f);
    u += 0x7FFFu + ((u >> 16) & 1u);   // RNE
    return (unsigned short)(u >> 16);
}
__device__ __forceinline__ float bf2f(unsigned short s) {
    return __uint_as_float(((u32)s) << 16);
}
__device__ __forceinline__ u32 pk2(float lo, float hi) {
    __hip_bfloat162 h = __float22bfloat162_rn(float2{lo, hi});  // v_cvt_pk_bf16_f32
    return *(u32*)&h;
}
__device__ __forceinline__ u64 pack4(f32x4 v) {
    return (u64)pk2(v.x, v.y) | ((u64)pk2(v.z, v.w) << 32);
}
__device__ __forceinline__ float fast_tanh(float x) {
    return 1.f - 2.f * __builtin_amdgcn_rcpf(__expf(2.f * x) + 1.f);
}
__device__ __forceinline__ float fast_sigmoid(float x) {
    return __builtin_amdgcn_rcpf(1.f + __expf(-x));
}
// async global->LDS DMA, 16B per lane: LDS dest = uniform base + lane*16 (linear),
// global src = per-lane address.
__device__ __forceinline__ void dma16(const float* g, float* l) {
    __builtin_amdgcn_global_load_lds((const __attribute__((address_space(1))) u32*)g,
                                     (__attribute__((address_space(3))) u32*)l, 16, 0, 0);
}

// W_update / W_gate (f32, [K][N]) -> bf16 transposed [N][K].
// ws layout: [0]=Wt_update, [1]=Wt_gate_top (k<256), [2]=Wt_gate_bot.
__global__ void convert_w(const float* __restrict__ Wu, const float* __restrict__ Wg,
                          unsigned short* __restrict__ wt) {
    int idx = blockIdx.x * 256 + threadIdx.x;
    if (idx >= 3 * 65536) return;
    int m = idx >> 16;
    int r = idx & 65535;
    int n = r >> 8;
    int k = r & 255;
    float v;
    if (m == 0)      v = Wu[k * 256 + n];
    else if (m == 1) v = Wg[k * 256 + n];
    else             v = Wg[(k + 256) * 256 + n];
    wt[idx] = f2bf(v);
}

__global__ void set_mask(const int* __restrict__ keys, unsigned char* __restrict__ mask) {
    int i = blockIdx.x * 256 + threadIdx.x;
    if (i < NR_MAP) mask[keys[i]] = 1;
}

__global__ void copy_unmapped(const float* __restrict__ prev,
                              const unsigned char* __restrict__ mask,
                              float* __restrict__ out) {
    const long long total = (long long)NR_AST * 64;  // f32x4 units
    for (long long i = (long long)blockIdx.x * blockDim.x + threadIdx.x; i < total;
         i += (long long)gridDim.x * blockDim.x) {
        int row = (int)(i >> 6);
        if (!mask[row]) {
            f32x4 v = __builtin_nontemporal_load((const f32x4*)prev + i);
            __builtin_nontemporal_store(v, (f32x4*)out + i);
        }
    }
}

// Persistent DMA-pipelined mixer. 256 blocks x 512 threads (8 waves), 32 rows/tile,
// ~49 tiles/block. Next tile's gathers stream into an LDS f32 stage via
// global_load_lds (no staging VGPRs -> no spill) while the current tile computes.
// All three weight matrices are register-resident (192 VGPR) so the steady loop
// has NO compiler-waited global loads that would drain the async gathers;
// the single drain point is vmcnt(0) at tile entry.
__global__ __launch_bounds__(512, 2) void mixer_main(
    const float* __restrict__ prev, const float* __restrict__ cfg,
    const int* __restrict__ keys, const int* __restrict__ vals,
    const unsigned short* __restrict__ Wtu, const unsigned short* __restrict__ Wtgt,
    const unsigned short* __restrict__ Wtgb, const float* __restrict__ bu,
    const float* __restrict__ bg, float* __restrict__ out) {
    __shared__ __align__(16) float stage_c[BM][256];           // 32 KB f32 DMA stage (linear)
    __shared__ __align__(16) float stage_p[BM][256];           // 32 KB
    __shared__ __align__(16) unsigned char ctxb[BM * 512];     // bf16 ctx tile, then u (aliased)
    __shared__ __align__(16) unsigned char prvb[BM * 512];     // bf16 prev tile

    const int tid = threadIdx.x;
    const int lane = tid & 63;
    const int wv = __builtin_amdgcn_readfirstlane(tid >> 6);   // 0..7, SGPR
    const int ln15 = lane & 15;
    const int khi = lane >> 4;
    const int ln31 = lane & 31;
    const int cb = wv * 32;   // this wave's output column base

    // ---- one-time: all B fragments into registers (48 short8 = 192 VGPR) ----
    short8 wu_r[8][2], wgt_r[8][2], wgb_r[8][2];
#pragma unroll
    for (int ks = 0; ks < 8; ++ks)
#pragma unroll
        for (int nt = 0; nt < 2; ++nt) {
            int col = cb + nt * 16 + ln15;
            wu_r[ks][nt]  = *(const short8*)(Wtu  + col * 256 + ks * 32 + khi * 8);
            wgt_r[ks][nt] = *(const short8*)(Wtgt + col * 256 + ks * 32 + khi * 8);
            wgb_r[ks][nt] = *(const short8*)(Wtgb + col * 256 + ks * 32 + khi * 8);
        }
    const float bu0 = bu[cb + ln15], bu1 = bu[cb + 16 + ln15];
    const float bg0 = bg[cb + ln15], bg1 = bg[cb + 16 + ln15];

    int t = blockIdx.x;
    // ---- prologue: indices + DMA for tile t; indices for t+NBLK ----
    int kvC = keys[t * BM + ln31];
    int vvC = vals[t * BM + ln31];
#pragma unroll
    for (int i = 0; i < 4; ++i) {
        int r = wv * 4 + i;
        int v = __shfl(vvC, r);
        int k = __shfl(kvC, r);
        dma16(cfg  + (size_t)v * AST_DIM + lane * 4, &stage_c[r][0]);
        dma16(prev + (size_t)k * AST_DIM + lane * 4, &stage_p[r][0]);
    }
    int t1 = t + NBLK; if (t1 >= NT_TILES) t1 = NT_TILES - 1;
    int kvN = keys[t1 * BM + ln31];
    int vvN = vals[t1 * BM + ln31];

#pragma unroll 1
    for (; t < NT_TILES; t += NBLK) {
        // ---- entry: drain own DMA (and old stores); nothing useful in flight ----
        asm volatile("s_waitcnt vmcnt(0)" ::: "memory");
        __builtin_amdgcn_s_barrier();      // all waves' DMA rows visible

        // ---- convert stage f32 -> swizzled bf16 tiles ----
#pragma unroll
        for (int c = 0; c < 8; ++c) {
            int r = c * 8 + wv;
            f32x4 vc = *(const f32x4*)((const char*)stage_c + c * 8192 + tid * 16);
            f32x4 vp = *(const f32x4*)((const char*)stage_p + c * 8192 + tid * 16);
            int dst = (r << 9) + ((lane << 3) ^ ((r & 7) << 4));
            *(u64*)(ctxb + dst) = pack4(vc);
            *(u64*)(prvb + dst) = pack4(vp);
        }
        asm volatile("s_waitcnt lgkmcnt(0)" ::: "memory");
        __builtin_amdgcn_s_barrier();      // bf16 tiles ready; stage is free

        // ---- issue DMA for next tile into the (now free) stage ----
#pragma unroll
        for (int i = 0; i < 4; ++i) {
            int r = wv * 4 + i;
            int v = __shfl(vvN, r);
            int k = __shfl(kvN, r);
            dma16(cfg  + (size_t)v * AST_DIM + lane * 4, &stage_c[r][0]);
            dma16(prev + (size_t)k * AST_DIM + lane * 4, &stage_p[r][0]);
        }
        // indices two iterations ahead
        int t2 = t + 2 * NBLK; if (t2 >= NT_TILES) t2 = NT_TILES - 1;
        int kvL = keys[t2 * BM + ln31];
        int vvL = vals[t2 * BM + ln31];

        // ---- GEMM1: u_pre = ctx @ Wu + bu ----
        f32x4 acc[2][2];
        acc[0][0] = f32x4{bu0, bu0, bu0, bu0};
        acc[0][1] = f32x4{bu1, bu1, bu1, bu1};
        acc[1][0] = acc[0][0];
        acc[1][1] = acc[0][1];
#pragma unroll
        for (int ks = 0; ks < 8; ++ks) {
            short8 a[2];
#pragma unroll
            for (int mt = 0; mt < 2; ++mt) {
                int row = mt * 16 + ln15;
                int addr = (row << 9) + (ks << 6) + (khi << 4);
                addr ^= (row & 7) << 4;
                a[mt] = *(const short8*)(ctxb + addr);
            }
#pragma unroll
            for (int mt = 0; mt < 2; ++mt)
#pragma unroll
                for (int nt = 0; nt < 2; ++nt)
                    acc[mt][nt] = __builtin_amdgcn_mfma_f32_16x16x32_bf16(a[mt], wu_r[ks][nt], acc[mt][nt], 0, 0, 0);
        }
        __builtin_amdgcn_s_barrier();      // all waves done reading ctx tile

        // ---- tanh; write u (bf16) into ctxb (aliased) ----
#pragma unroll
        for (int mt = 0; mt < 2; ++mt)
#pragma unroll
            for (int rr = 0; rr < 4; ++rr) {
                int row = mt * 16 + khi * 4 + rr;
#pragma unroll
                for (int nt = 0; nt < 2; ++nt) {
                    int col = cb + nt * 16 + ln15;
                    int addr = (row << 9) + (col << 1);
                    addr ^= (row & 7) << 4;
                    *(unsigned short*)(ctxb + addr) = f2bf(fast_tanh(acc[mt][nt][rr]));
                }
            }
        asm volatile("s_waitcnt lgkmcnt(0)" ::: "memory");
        __builtin_amdgcn_s_barrier();      // u visible

        // ---- GEMM2: z_pre = prev @ Wg_top + u @ Wg_bot + bg ----
        acc[0][0] = f32x4{bg0, bg0, bg0, bg0};
        acc[0][1] = f32x4{bg1, bg1, bg1, bg1};
        acc[1][0] = acc[0][0];
        acc[1][1] = acc[0][1];
#pragma unroll
        for (int ks = 0; ks < 8; ++ks) {
            short8 a[2];
#pragma unroll
            for (int mt = 0; mt < 2; ++mt) {
                int row = mt * 16 + ln15;
                int addr = (row << 9) + (ks << 6) + (khi << 4);
                addr ^= (row & 7) << 4;
                a[mt] = *(const short8*)(prvb + addr);
            }
#pragma unroll
            for (int mt = 0; mt < 2; ++mt)
#pragma unroll
                for (int nt = 0; nt < 2; ++nt)
                    acc[mt][nt] = __builtin_amdgcn_mfma_f32_16x16x32_bf16(a[mt], wgt_r[ks][nt], acc[mt][nt], 0, 0, 0);
        }
#pragma unroll
        for (int ks = 0; ks < 8; ++ks) {
            short8 a[2];
#pragma unroll
            for (int mt = 0; mt < 2; ++mt) {
                int row = mt * 16 + ln15;
                int addr = (row << 9) + (ks << 6) + (khi << 4);
                addr ^= (row & 7) << 4;
                a[mt] = *(const short8*)(ctxb + addr);   // u
            }
#pragma unroll
            for (int mt = 0; mt < 2; ++mt)
#pragma unroll
                for (int nt = 0; nt < 2; ++nt)
                    acc[mt][nt] = __builtin_amdgcn_mfma_f32_16x16x32_bf16(a[mt], wgb_r[ks][nt], acc[mt][nt], 0, 0, 0);
        }

        // ---- epilogue: sigmoid, blend, scatter store ----
#pragma unroll
        for (int mt = 0; mt < 2; ++mt)
#pragma unroll
            for (int rr = 0; rr < 4; ++rr) {
                int row = mt * 16 + khi * 4 + rr;
                int key = __shfl(kvC, row);
                float* orow = out + (size_t)key * AST_DIM;
#pragma unroll
                for (int nt = 0; nt < 2; ++nt) {
                    int col = cb + nt * 16 + ln15;
                    int ad = (row << 9) + (col << 1);
                    ad ^= (row & 7) << 4;
                    float z = fast_sigmoid(acc[mt][nt][rr]);
                    float pf = bf2f(*(const unsigned short*)(prvb + ad));
                    float uv = bf2f(*(const unsigned short*)(ctxb + ad));
                    __builtin_nontemporal_store(fmaf(z, pf - uv, uv), orow + col);
                }
            }

        // rotate index registers (tile-t reads done; next entry barrier protects LDS)
        kvC = kvN; kvN = kvL; vvN = vvL;
    }
}

extern "C" void kernel_launch(void* const* d_in, const int* in_sizes, int n_in,
                              void* d_out, int out_size, void* d_ws, size_t ws_size,
                              hipStream_t stream) {
    const float* prev = (const float*)d_in[0];
    const float* cfg = (const float*)d_in[1];
    const int* keys = (const int*)d_in[2];
    const int* vals = (const int*)d_in[3];
    const float* Wu = (const float*)d_in[4];
    const float* bu = (const float*)d_in[5];
    const float* Wg = (const float*)d_in[6];
    const float* bg = (const float*)d_in[7];
    float* out = (float*)d_out;

    unsigned short* wt = (unsigned short*)d_ws;                    // 3*65536 bf16
    unsigned char* mask = (unsigned char*)d_ws + 3 * 65536 * 2;    // NR_AST bytes

    (void)hipMemsetAsync(mask, 0, NR_AST, stream);
    convert_w<<<768, 256, 0, stream>>>(Wu, Wg, wt);
    set_mask<<<(NR_MAP + 255) / 256, 256, 0, stream>>>(keys, mask);
    copy_unmapped<<<2048, 256, 0, stream>>>(prev, mask, out);
    mixer_main<<<NBLK, 512, 0, stream>>>(prev, cfg, keys, vals, wt, wt + 65536,
                                         wt + 2 * 65536, bu, bg, out);
}

// Round 7
// 442.660 us; speedup vs baseline: 3.5785x; 1.7895x over previous
//
#include <hip/hip_runtime.h>
#include <hip/hip_bf16.h>

#define AST_DIM 256
#define NR_AST 500000
#define NR_CFG 100000
#define NR_MAP 400000

typedef short short8 __attribute__((ext_vector_type(8)));
typedef float f32x4 __attribute__((ext_vector_type(4)));
typedef unsigned long long u64;
typedef unsigned int u32;

__device__ __forceinline__ unsigned short f2bf(float f) {
    u32 u = __float_as_uint(f);
    u += 0x7FFFu + ((u >> 16) & 1u);   // RNE
    return (unsigned short)(u >> 16);
}
__device__ __forceinline__ float bf2f(unsigned short s) {
    return __uint_as_float(((u32)s) << 16);
}
__device__ __forceinline__ u64 pack4(f32x4 v) {
    __hip_bfloat162 lo = __float22bfloat162_rn(float2{v.x, v.y});  // v_cvt_pk_bf16_f32
    __hip_bfloat162 hi = __float22bfloat162_rn(float2{v.z, v.w});
    return (u64)(*(u32*)&lo) | ((u64)(*(u32*)&hi) << 32);
}
__device__ __forceinline__ float fast_tanh(float x) {
    return 1.f - 2.f * __builtin_amdgcn_rcpf(__expf(2.f * x) + 1.f);
}
__device__ __forceinline__ float fast_sigmoid(float x) {
    return __builtin_amdgcn_rcpf(1.f + __expf(-x));
}
// async global->LDS DMA, 16B/lane: LDS dest = wave-uniform base + lane*16 (linear);
// global src is per-lane (enables source-side swizzling).
__device__ __forceinline__ void dma16(const void* g, void* l) {
    __builtin_amdgcn_global_load_lds((const __attribute__((address_space(1))) u32*)g,
                                     (__attribute__((address_space(3))) u32*)l, 16, 0, 0);
}

// W_update / W_gate (f32, [K][N]) -> bf16 transposed [N][K].
// ws layout: [0]=Wt_update, [1]=Wt_gate_top (k<256), [2]=Wt_gate_bot.
__global__ void convert_w(const float* __restrict__ Wu, const float* __restrict__ Wg,
                          unsigned short* __restrict__ wt) {
    int idx = blockIdx.x * 256 + threadIdx.x;
    if (idx >= 3 * 65536) return;
    int m = idx >> 16;
    int r = idx & 65535;
    int n = r >> 8;
    int k = r & 255;
    float v;
    if (m == 0)      v = Wu[k * 256 + n];
    else if (m == 1) v = Wg[k * 256 + n];
    else             v = Wg[(k + 256) * 256 + n];
    wt[idx] = f2bf(v);
}

__global__ void set_mask(const int* __restrict__ keys, unsigned char* __restrict__ mask) {
    int i = blockIdx.x * 256 + threadIdx.x;
    if (i < NR_MAP) mask[keys[i]] = 1;
}

__global__ void copy_unmapped(const float* __restrict__ prev,
                              const unsigned char* __restrict__ mask,
                              float* __restrict__ out) {
    const long long total = (long long)NR_AST * 64;  // f32x4 units
    for (long long i = (long long)blockIdx.x * blockDim.x + threadIdx.x; i < total;
         i += (long long)gridDim.x * blockDim.x) {
        int row = (int)(i >> 6);
        if (!mask[row]) {
            f32x4 v = __builtin_nontemporal_load((const f32x4*)prev + i);
            __builtin_nontemporal_store(v, (f32x4*)out + i);
        }
    }
}

// Pass A: u_all[c] = tanh(cfg[c] @ Wu + bu) for ALL 100K cfg rows (dense stream,
// no gathers). 64 rows/block, 512 thr (8 waves x 32 cols).
__global__ __launch_bounds__(512, 4) void compute_u(
    const float* __restrict__ cfg, const unsigned short* __restrict__ Wtu,
    const float* __restrict__ bu, unsigned short* __restrict__ u_all) {
    __shared__ __align__(16) unsigned char ctxb[64 * 512];  // bf16 swizzled tile

    const int tid = threadIdx.x;
    const int lane = tid & 63;
    const int wv = tid >> 6;
    const int ln15 = lane & 15;
    const int khi = lane >> 4;
    const int cb = wv * 32;
    const int m0 = blockIdx.x * 64;

#pragma unroll
    for (int i = 0; i < 8; ++i) {
        int r = wv * 8 + i;
        int g = m0 + r;
        if (g >= NR_CFG) g = NR_CFG - 1;
        f32x4 v = *((const f32x4*)(cfg + (size_t)g * AST_DIM) + lane);
        int addr = (r << 9) + ((lane << 3) ^ ((r & 7) << 4));
        *(u64*)(ctxb + addr) = pack4(v);
    }
    __syncthreads();

    const float b0 = bu[cb + ln15], b1 = bu[cb + 16 + ln15];
    f32x4 acc[4][2];
#pragma unroll
    for (int mt = 0; mt < 4; ++mt) {
        acc[mt][0] = f32x4{b0, b0, b0, b0};
        acc[mt][1] = f32x4{b1, b1, b1, b1};
    }
#pragma unroll
    for (int ks = 0; ks < 8; ++ks) {
        short8 a[4], b[2];
#pragma unroll
        for (int mt = 0; mt < 4; ++mt) {
            int row = mt * 16 + ln15;
            int addr = (row << 9) + (((ks << 6) + (khi << 4)) ^ ((row & 7) << 4));
            a[mt] = *(const short8*)(ctxb + addr);
        }
#pragma unroll
        for (int nt = 0; nt < 2; ++nt)
            b[nt] = *(const short8*)(Wtu + (cb + nt * 16 + ln15) * 256 + ks * 32 + khi * 8);
#pragma unroll
        for (int mt = 0; mt < 4; ++mt)
#pragma unroll
            for (int nt = 0; nt < 2; ++nt)
                acc[mt][nt] = __builtin_amdgcn_mfma_f32_16x16x32_bf16(a[mt], b[nt], acc[mt][nt], 0, 0, 0);
    }
#pragma unroll
    for (int mt = 0; mt < 4; ++mt)
#pragma unroll
        for (int rr = 0; rr < 4; ++rr) {
            int row = mt * 16 + khi * 4 + rr;
            int g = m0 + row;
            if (g < NR_CFG) {
#pragma unroll
                for (int nt = 0; nt < 2; ++nt) {
                    int col = cb + nt * 16 + ln15;
                    u_all[(size_t)g * AST_DIM + col] = f2bf(fast_tanh(acc[mt][nt][rr]));
                }
            }
        }
}

// Main: gather prev(f32->bf16 reg-pack) + u(bf16, DMA with source-side swizzle),
// one barrier, fused GEMM2 (K=512) + sigmoid blend + scatter store.
// 6250 blocks x 512 thr (8 waves x 32 cols), 64 rows/block, 64KB LDS -> 2 blk/CU.
__global__ __launch_bounds__(512, 4) void mixer_gate(
    const float* __restrict__ prev, const unsigned short* __restrict__ u_all,
    const int* __restrict__ keys, const int* __restrict__ vals,
    const unsigned short* __restrict__ Wtgt, const unsigned short* __restrict__ Wtgb,
    const float* __restrict__ bg, float* __restrict__ out) {
    __shared__ __align__(16) unsigned char prvb[64 * 512];  // bf16 swizzled prev tile
    __shared__ __align__(16) unsigned char u_st[64 * 512];  // bf16 swizzled u tile

    const int tid = threadIdx.x;
    const int lane = tid & 63;
    const int wv = tid >> 6;
    const int ln15 = lane & 15;
    const int khi = lane >> 4;
    const int cb = wv * 32;
    const int m0 = blockIdx.x * 64;

    const int kv = keys[m0 + lane];
    const int vv = vals[m0 + lane];

    // ---- u gathers: async DMA, 2 rows per instr; swizzle applied on the SOURCE
    // (LDS dest must be linear). LDS[row][chunk c] <- global chunk c^(row&7).
#pragma unroll
    for (int i = 0; i < 4; ++i) {
        int r0 = wv * 8 + i * 2;
        int row = r0 + (lane >> 5);
        int vidx = __shfl(vv, row);
        const unsigned short* src = u_all + (size_t)vidx * AST_DIM + (((lane & 31) ^ (row & 7)) << 3);
        dma16(src, u_st + (r0 << 9));
    }
    // ---- prev gathers: f32x4 -> bf16 pack -> swizzled LDS (DMA flies underneath)
#pragma unroll
    for (int i = 0; i < 8; ++i) {
        int r = wv * 8 + i;
        int kidx = __shfl(kv, r);
        f32x4 v = *((const f32x4*)(prev + (size_t)kidx * AST_DIM) + lane);
        int addr = (r << 9) + ((lane << 3) ^ ((r & 7) << 4));
        *(u64*)(prvb + addr) = pack4(v);
    }
    __syncthreads();   // drains DMA (vmcnt) + packs (lgkmcnt); the ONLY barrier

    // ---- GEMM2: z_pre = prev @ Wg_top + u @ Wg_bot + bg ----
    const float b0 = bg[cb + ln15], b1 = bg[cb + 16 + ln15];
    f32x4 acc[4][2];
#pragma unroll
    for (int mt = 0; mt < 4; ++mt) {
        acc[mt][0] = f32x4{b0, b0, b0, b0};
        acc[mt][1] = f32x4{b1, b1, b1, b1};
    }
#pragma unroll
    for (int ks = 0; ks < 8; ++ks) {
        short8 a[4], b[2];
#pragma unroll
        for (int mt = 0; mt < 4; ++mt) {
            int row = mt * 16 + ln15;
            int addr = (row << 9) + (((ks << 6) + (khi << 4)) ^ ((row & 7) << 4));
            a[mt] = *(const short8*)(prvb + addr);
        }
#pragma unroll
        for (int nt = 0; nt < 2; ++nt)
            b[nt] = *(const short8*)(Wtgt + (cb + nt * 16 + ln15) * 256 + ks * 32 + khi * 8);
#pragma unroll
        for (int mt = 0; mt < 4; ++mt)
#pragma unroll
            for (int nt = 0; nt < 2; ++nt)
                acc[mt][nt] = __builtin_amdgcn_mfma_f32_16x16x32_bf16(a[mt], b[nt], acc[mt][nt], 0, 0, 0);
    }
#pragma unroll
    for (int ks = 0; ks < 8; ++ks) {
        short8 a[4], b[2];
#pragma unroll
        for (int mt = 0; mt < 4; ++mt) {
            int row = mt * 16 + ln15;
            int addr = (row << 9) + ((((ks << 2) + khi) ^ (row & 7)) << 4);
            a[mt] = *(const short8*)(u_st + addr);
        }
#pragma unroll
        for (int nt = 0; nt < 2; ++nt)
            b[nt] = *(const short8*)(Wtgb + (cb + nt * 16 + ln15) * 256 + ks * 32 + khi * 8);
#pragma unroll
        for (int mt = 0; mt < 4; ++mt)
#pragma unroll
            for (int nt = 0; nt < 2; ++nt)
                acc[mt][nt] = __builtin_amdgcn_mfma_f32_16x16x32_bf16(a[mt], b[nt], acc[mt][nt], 0, 0, 0);
    }

    // ---- epilogue: z = sigmoid, blend, scatter store (no barrier needed) ----
#pragma unroll
    for (int mt = 0; mt < 4; ++mt)
#pragma unroll
        for (int rr = 0; rr < 4; ++rr) {
            int row = mt * 16 + khi * 4 + rr;
            int key = __shfl(kv, row);
            float* orow = out + (size_t)key * AST_DIM;
#pragma unroll
            for (int nt = 0; nt < 2; ++nt) {
                int col = cb + nt * 16 + ln15;
                float z = fast_sigmoid(acc[mt][nt][rr]);
                float pf = bf2f(*(const unsigned short*)(prvb + (row << 9) + ((col << 1) ^ ((row & 7) << 4))));
                float uv = bf2f(*(const unsigned short*)(u_st + (row << 9) +
                                ((((col >> 3) ^ (row & 7)) << 4) + ((col & 7) << 1))));
                orow[col] = fmaf(z, pf - uv, uv);  // z*prev + (1-z)*u
            }
        }
}

// Fallback (ws too small for u_all): round-1 fused kernel — known-good, 505us.
__global__ __launch_bounds__(512, 4) void mixer_fused(
    const float* __restrict__ prev, const float* __restrict__ cfg,
    const int* __restrict__ keys, const int* __restrict__ vals,
    const unsigned short* __restrict__ Wtu, const unsigned short* __restrict__ Wtgt,
    const unsigned short* __restrict__ Wtgb, const float* __restrict__ bu,
    const float* __restrict__ bg, float* __restrict__ out) {
    __shared__ __align__(16) unsigned char ctx_lds[64 * 512];
    __shared__ __align__(16) unsigned char prv_lds[64 * 512];

    const int tid = threadIdx.x;
    const int lane = tid & 63;
    const int wave = tid >> 6;
    const int ln15 = lane & 15;
    const int khi = lane >> 4;
    const int cb = wave * 32;
    const int m0 = blockIdx.x * 64;

    const int kv = keys[m0 + lane];
    const int vv = vals[m0 + lane];

#pragma unroll 4
    for (int i = 0; i < 8; ++i) {
        int r = i * 8 + wave;
        f32x4 cv = *((const f32x4*)(cfg + (size_t)__shfl(vv, r) * AST_DIM) + lane);
        f32x4 pv = *((const f32x4*)(prev + (size_t)__shfl(kv, r) * AST_DIM) + lane);
        int addr = (r << 9) + ((lane << 3) ^ ((r & 7) << 4));
        *(u64*)(ctx_lds + addr) = pack4(cv);
        *(u64*)(prv_lds + addr) = pack4(pv);
    }
    __syncthreads();

    f32x4 acc[4][2];
    {
        float b0 = bu[cb + ln15], b1 = bu[cb + 16 + ln15];
        for (int mt = 0; mt < 4; ++mt) {
            acc[mt][0] = f32x4{b0, b0, b0, b0};
            acc[mt][1] = f32x4{b1, b1, b1, b1};
        }
    }
#pragma unroll
    for (int ks = 0; ks < 8; ++ks) {
        short8 a[4], b[2];
        for (int mt = 0; mt < 4; ++mt) {
            int row = mt * 16 + ln15;
            int addr = (row << 9) + (((ks << 6) + (khi << 4)) ^ ((row & 7) << 4));
            a[mt] = *(const short8*)(ctx_lds + addr);
        }
        for (int nt = 0; nt < 2; ++nt)
            b[nt] = *(const short8*)(Wtu + (cb + nt * 16 + ln15) * 256 + ks * 32 + khi * 8);
        for (int mt = 0; mt < 4; ++mt)
            for (int nt = 0; nt < 2; ++nt)
                acc[mt][nt] = __builtin_amdgcn_mfma_f32_16x16x32_bf16(a[mt], b[nt], acc[mt][nt], 0, 0, 0);
    }
    __syncthreads();
#pragma unroll
    for (int mt = 0; mt < 4; ++mt)
        for (int rr = 0; rr < 4; ++rr) {
            int row = mt * 16 + khi * 4 + rr;
            for (int nt = 0; nt < 2; ++nt) {
                int col = cb + nt * 16 + ln15;
                int addr = (row << 9) + ((col << 1) ^ ((row & 7) << 4));
                *(unsigned short*)(ctx_lds + addr) = f2bf(fast_tanh(acc[mt][nt][rr]));
            }
        }
    __syncthreads();
    {
        float b0 = bg[cb + ln15], b1 = bg[cb + 16 + ln15];
        for (int mt = 0; mt < 4; ++mt) {
            acc[mt][0] = f32x4{b0, b0, b0, b0};
            acc[mt][1] = f32x4{b1, b1, b1, b1};
        }
    }
#pragma unroll
    for (int ks = 0; ks < 8; ++ks) {
        short8 a[4], b[2];
        for (int mt = 0; mt < 4; ++mt) {
            int row = mt * 16 + ln15;
            int addr = (row << 9) + (((ks << 6) + (khi << 4)) ^ ((row & 7) << 4));
            a[mt] = *(const short8*)(prv_lds + addr);
        }
        for (int nt = 0; nt < 2; ++nt)
            b[nt] = *(const short8*)(Wtgt + (cb + nt * 16 + ln15) * 256 + ks * 32 + khi * 8);
        for (int mt = 0; mt < 4; ++mt)
            for (int nt = 0; nt < 2; ++nt)
                acc[mt][nt] = __builtin_amdgcn_mfma_f32_16x16x32_bf16(a[mt], b[nt], acc[mt][nt], 0, 0, 0);
    }
#pragma unroll
    for (int ks = 0; ks < 8; ++ks) {
        short8 a[4], b[2];
        for (int mt = 0; mt < 4; ++mt) {
            int row = mt * 16 + ln15;
            int addr = (row << 9) + (((ks << 6) + (khi << 4)) ^ ((row & 7) << 4));
            a[mt] = *(const short8*)(ctx_lds + addr);
        }
        for (int nt = 0; nt < 2; ++nt)
            b[nt] = *(const short8*)(Wtgb + (cb + nt * 16 + ln15) * 256 + ks * 32 + khi * 8);
        for (int mt = 0; mt < 4; ++mt)
            for (int nt = 0; nt < 2; ++nt)
                acc[mt][nt] = __builtin_amdgcn_mfma_f32_16x16x32_bf16(a[mt], b[nt], acc[mt][nt], 0, 0, 0);
    }
#pragma unroll
    for (int mt = 0; mt < 4; ++mt)
        for (int rr = 0; rr < 4; ++rr) {
            int row = mt * 16 + khi * 4 + rr;
            int key = __shfl(kv, row);
            float* orow = out + (size_t)key * AST_DIM;
            for (int nt = 0; nt < 2; ++nt) {
                int col = cb + nt * 16 + ln15;
                int ad = (row << 9) + ((col << 1) ^ ((row & 7) << 4));
                float z = fast_sigmoid(acc[mt][nt][rr]);
                float pf = bf2f(*(const unsigned short*)(prv_lds + ad));
                float uv = bf2f(*(const unsigned short*)(ctx_lds + ad));
                orow[col] = fmaf(z, pf - uv, uv);
            }
        }
}

extern "C" void kernel_launch(void* const* d_in, const int* in_sizes, int n_in,
                              void* d_out, int out_size, void* d_ws, size_t ws_size,
                              hipStream_t stream) {
    const float* prev = (const float*)d_in[0];
    const float* cfg = (const float*)d_in[1];
    const int* keys = (const int*)d_in[2];
    const int* vals = (const int*)d_in[3];
    const float* Wu = (const float*)d_in[4];
    const float* bu = (const float*)d_in[5];
    const float* Wg = (const float*)d_in[6];
    const float* bg = (const float*)d_in[7];
    float* out = (float*)d_out;

    // ws: [0, 384KB) wt | [384KB, ~884KB) mask | [1MB, 1MB+51.2MB) u_all
    unsigned short* wt = (unsigned short*)d_ws;
    unsigned char* mask = (unsigned char*)d_ws + 3 * 65536 * 2;
    unsigned short* u_all = (unsigned short*)((char*)d_ws + (1 << 20));
    const size_t ws_needed = (size_t)(1 << 20) + (size_t)NR_CFG * AST_DIM * 2;  // ~52.3 MB

    (void)hipMemsetAsync(mask, 0, NR_AST, stream);
    convert_w<<<768, 256, 0, stream>>>(Wu, Wg, wt);
    set_mask<<<(NR_MAP + 255) / 256, 256, 0, stream>>>(keys, mask);
    copy_unmapped<<<2048, 256, 0, stream>>>(prev, mask, out);
    if (ws_size >= ws_needed) {
        compute_u<<<(NR_CFG + 63) / 64, 512, 0, stream>>>(cfg, wt, bu, u_all);
        mixer_gate<<<NR_MAP / 64, 512, 0, stream>>>(prev, u_all, keys, vals,
                                                    wt + 65536, wt + 2 * 65536, bg, out);
    } else {
        mixer_fused<<<NR_MAP / 64, 512, 0, stream>>>(prev, cfg, keys, vals, wt, wt + 65536,
                                                     wt + 2 * 65536, bu, bg, out);
    }
}